// Round 4
// baseline (6307.258 us; speedup 1.0000x reference)
//
#include <hip/hip_runtime.h>
#include <hip/hip_bf16.h>

typedef __bf16 bf16x8 __attribute__((ext_vector_type(8)));
typedef float  f32x4  __attribute__((ext_vector_type(4)));

#define MFMA_BF16(a, b, c) __builtin_amdgcn_mfma_f32_16x16x32_bf16((a), (b), (c), 0, 0, 0)

constexpr int TT = 160, BB = 2048, HH = 512, EE = 64, VV = 128, G3 = 1536;
constexpr size_t LPROB_ELEMS = (size_t)TT * BB * VV;  // 41,943,040

__device__ __forceinline__ float fsigmoid(float x) {
  return 1.0f / (1.0f + __expf(-x));
}
__device__ __forceinline__ float ftanh(float x) {
  float ax = fabsf(x);
  float e = __expf(-2.0f * ax);
  float r = (1.0f - e) / (1.0f + e);
  return x < 0.0f ? -r : r;
}

// device-scope sync helpers (inter-workgroup, cross-XCD safe per G16)
__device__ __forceinline__ void spin_ge(int* p, int target) {
  while (__hip_atomic_load(p, __ATOMIC_RELAXED, __HIP_MEMORY_SCOPE_AGENT) < target)
    __builtin_amdgcn_s_sleep(2);
}
__device__ __forceinline__ void arrive(int* p) {
  __hip_atomic_fetch_add(p, 1, __ATOMIC_RELEASE, __HIP_MEMORY_SCOPE_AGENT);
}

// ---------------- prep kernels (fp32 inputs confirmed in round 3) ----------------

// Whh_b/Wout_b bf16 copies, bhhn_f/bout_f f32, zero the barrier counters.
__global__ __launch_bounds__(256) void conv_w(
    const float* __restrict__ Whh, const float* __restrict__ Wout,
    const float* __restrict__ bhh, const float* __restrict__ bout,
    __bf16* __restrict__ Whh_b, __bf16* __restrict__ Wout_b,
    float* __restrict__ bhhn_f, float* __restrict__ bout_f,
    int* __restrict__ bar) {
  int idx = blockIdx.x * 256 + threadIdx.x;   // 3072 blocks -> 786,432 = 1536*512
  Whh_b[idx] = (__bf16)Whh[idx];
  if (idx < VV * HH) Wout_b[idx] = (__bf16)Wout[idx];
  if (idx < HH) bhhn_f[idx] = bhh[2 * HH + idx];
  if (idx < VV) bout_f[idx] = bout[idx];
  if (idx < 512) bar[idx] = 0;
}

// gi_vocab[v][n] = relu(emb[v]) . W_ih[n] + b_ih[n] + (n < 1024 ? b_hh[n] : 0)
// (b_hh n-slice NOT folded: it sits inside r * (gh_n + b_hh_n))
__global__ __launch_bounds__(256) void prep_gi(
    const float* __restrict__ emb, const float* __restrict__ Wih,
    const float* __restrict__ bih, const float* __restrict__ bhh,
    float* __restrict__ gi) {
  int idx = blockIdx.x * 256 + threadIdx.x;   // 768 blocks -> exactly 128*1536
  int v = idx / G3;
  int n = idx - v * G3;
  const float* er = emb + v * EE;
  const float* wr = Wih + (size_t)n * EE;
  float s = 0.0f;
#pragma unroll 8
  for (int k = 0; k < EE; ++k) {
    float x = er[k];
    x = x > 0.0f ? x : 0.0f;
    s += x * wr[k];
  }
  s += bih[n];
  if (n < 2 * HH) s += bhh[n];
  gi[idx] = s;
}

// h0 bf16 mirror for MFMA (f32 state lives in gru_persist registers)
__global__ __launch_bounds__(256) void prep_h0(
    const float* __restrict__ ehid, __bf16* __restrict__ hb0) {
  int idx = blockIdx.x * 256 + threadIdx.x;   // 4096 blocks -> 1,048,576
  hb0[idx] = (__bf16)ehid[idx];
}

// ---------------- persistent kernel ----------------
// Grid 640 x 256, ONE launch for all 160 steps.
// Phase-1 blocks [0,512): grp = bid&15 (128 rows), colTile = bid>>4 (16 h-cols).
//   All 32 blocks of a group share bid%8 -> same XCD under round-robin dispatch
//   (perf heuristic only; correctness via agent-scope fences).
// Phase-2 blocks [512,640): 8 per group (also XCD-aligned: (bid-512)&15 = grp,
//   bid%8 = grp&7), each does logits+log_softmax for 16 rows, one step behind.
// Sync per group g: bar1[g] += 1 per phase-1 block per step (target 32(t+1));
//   bar2[g] += 1 per phase-2 block per step. Phase-1 at step t waits
//   bar2 >= 8(t-1) (phase-2 of step t-2 done) before overwriting the ping-pong
//   buffer it reads. No cycles -> deadlock-free. Capacity: 3 blocks/CU
//   (launch_bounds(256,3), LDS 49,920 B union) -> 768 slots >= 640 blocks.
// h fp32 state: 8 registers/thread (same (row,c) ownership every step).
// MFMA 16x16x32 bf16 layouts (HW-verified):
//   A/B: lane holds X[i=lane&15][k=quad*8+j]; D: col=lane&15, row=quad*4+reg.
__global__ __launch_bounds__(256, 3) void gru_persist(
    const __bf16* __restrict__ Whh_b, const __bf16* __restrict__ Wout_b,
    const float* __restrict__ bhhn_f, const float* __restrict__ bout_f,
    const float* __restrict__ gi, const int* __restrict__ tgt,
    const float* __restrict__ ehid,
    __bf16* __restrict__ hb0, __bf16* __restrict__ hb1,
    int* __restrict__ bar, float* __restrict__ outp) {
  __shared__ union {
    __bf16 w[48 * 520];   // 49,920 B: W_hh slice (phase-1)
    float  l[16 * 132];   //  8,448 B: logits scratch (phase-2)
  } sm;

  const int tid = threadIdx.x;
  const int bid = blockIdx.x;
  const int w = tid >> 6;
  const int lane = tid & 63;
  const int q = lane >> 4;
  const int l16 = lane & 15;
  const f32x4 fzero = {0.0f, 0.0f, 0.0f, 0.0f};

  if (bid < 512) {
    // ================= phase 1: recurrence =================
    const int grp = bid & 15;
    const int colTile = bid >> 4;
    const int mBase = grp * 128 + w * 32;
    const int c = colTile * 16 + l16;

    // stage W_hh slice into LDS once: row r = gate*16 + j <-> W_hh[gate*512 + colTile*16 + j]
    for (int idx = tid; idx < 48 * 64; idx += 256) {
      int r = idx >> 6;
      int ck = idx & 63;
      int gg = r >> 4;
      int j = r & 15;
      const __bf16* src = Whh_b + ((size_t)(gg * HH + colTile * 16 + j)) * HH + ck * 8;
      *(bf16x8*)&sm.w[r * 520 + ck * 8] = *(const bf16x8*)src;
    }

    // fp32 h state in registers: thread owns rows mBase+ms*16+q*4+rg, col c
    float hreg[8];
#pragma unroll
    for (int ms = 0; ms < 2; ++ms)
#pragma unroll
      for (int rg = 0; rg < 4; ++rg)
        hreg[ms * 4 + rg] = ehid[(size_t)(mBase + ms * 16 + q * 4 + rg) * HH + c];

    const float bhhn = bhhn_f[c];
    __syncthreads();

    for (int t = 0; t < TT; ++t) {
      const __bf16* hbs = (t & 1) ? hb1 : hb0;
      __bf16*       hbd = (t & 1) ? hb0 : hb1;

      // gh = h(t-1) @ W_hh^T : [128 x 48] tile, K=512, B from LDS
      f32x4 acc[2][3];
#pragma unroll
      for (int ms = 0; ms < 2; ++ms)
#pragma unroll
        for (int gg = 0; gg < 3; ++gg) acc[ms][gg] = fzero;

      const __bf16* aRow0 = hbs + (size_t)(mBase + l16) * HH + q * 8;
      const __bf16* aRow1 = aRow0 + 16 * HH;
      const __bf16* bBase = &sm.w[l16 * 520 + q * 8];

#pragma unroll 4
      for (int k0 = 0; k0 < HH; k0 += 32) {
        bf16x8 a0 = *(const bf16x8*)(aRow0 + k0);
        bf16x8 a1 = *(const bf16x8*)(aRow1 + k0);
#pragma unroll
        for (int gg = 0; gg < 3; ++gg) {
          bf16x8 bf = *(const bf16x8*)(bBase + gg * (16 * 520) + k0);
          acc[0][gg] = MFMA_BF16(a0, bf, acc[0][gg]);
          acc[1][gg] = MFMA_BF16(a1, bf, acc[1][gg]);
        }
      }

      // gates (D layout: col=lane&15, row=quad*4+reg)
#pragma unroll
      for (int ms = 0; ms < 2; ++ms) {
#pragma unroll
        for (int rg = 0; rg < 4; ++rg) {
          int row = mBase + ms * 16 + q * 4 + rg;
          int tk = (t == 0) ? 0 : tgt[row * TT + (t - 1)];
          const float* gv = gi + (size_t)tk * G3 + c;
          float r_ = fsigmoid(acc[ms][0][rg] + gv[0]);
          float z_ = fsigmoid(acc[ms][1][rg] + gv[HH]);
          float n_ = ftanh(gv[2 * HH] + r_ * (acc[ms][2][rg] + bhhn));
          float hv = (1.0f - z_) * n_ + z_ * hreg[ms * 4 + rg];
          hreg[ms * 4 + rg] = hv;
          size_t hi = (size_t)row * HH + c;
          hbd[hi] = (__bf16)hv;
          if (t == TT - 1) outp[LPROB_ELEMS + hi] = hv;   // final hidden (fp32)
        }
      }

      // group barrier: publish h(t), wait peers; WAR-gate on phase-2 (t-2)
      __syncthreads();   // compiler drains vmcnt before s_barrier -> stores in L2
      if (tid == 0) {
        arrive(&bar[grp * 32]);                        // bar1, release(agent)
        if (t < TT - 1) {
          spin_ge(&bar[grp * 32], 32 * (t + 1));       // h(t) complete
          if (t >= 1) spin_ge(&bar[grp * 32 + 16], 8 * t);  // phase-2 thru t-2... (8*(t+1-2)+8? see note)
          __builtin_amdgcn_fence(__ATOMIC_ACQUIRE, "agent");
        }
      }
      // note: next iteration (step t+1) overwrites hb[t&1], read by phase-2 of
      // step t-1. Gate: phase-2 steps 0..t-1 done -> bar2 >= 8*t. Checked above
      // at the END of step t (== before step t+1 starts). Exact, no slack lost.
      if (t < TT - 1) __syncthreads();
    }
  } else {
    // ================= phase 2: logits + log_softmax, one step behind =================
    const int pb = bid - 512;
    const int grp = pb & 15;
    const int j = pb >> 4;          // [0,8)
    const int rb = grp * 128 + j * 16;
    int* bar1 = &bar[grp * 32];
    int* bar2 = &bar[grp * 32 + 16];

    for (int t = 0; t < TT; ++t) {
      if (tid == 0) {
        spin_ge(bar1, 32 * (t + 1));                   // h(t) published
        __builtin_amdgcn_fence(__ATOMIC_ACQUIRE, "agent");
      }
      __syncthreads();

      const __bf16* hcur = ((t + 1) & 1) ? hb1 : hb0;  // h(t)
      f32x4 acc2[2];
      acc2[0] = fzero; acc2[1] = fzero;
      const __bf16* aR  = hcur + (size_t)(rb + l16) * HH + q * 8;
      const __bf16* bR0 = Wout_b + (size_t)(w * 32 + l16) * HH + q * 8;
      const __bf16* bR1 = bR0 + 16 * HH;
#pragma unroll 4
      for (int k0 = 0; k0 < HH; k0 += 32) {
        bf16x8 a  = *(const bf16x8*)(aR + k0);
        bf16x8 b0 = *(const bf16x8*)(bR0 + k0);
        bf16x8 b1 = *(const bf16x8*)(bR1 + k0);
        acc2[0] = MFMA_BF16(a, b0, acc2[0]);
        acc2[1] = MFMA_BF16(a, b1, acc2[1]);
      }
#pragma unroll
      for (int jj = 0; jj < 2; ++jj) {
        int col = (w * 2 + jj) * 16 + l16;
        float bo = bout_f[col];
#pragma unroll
        for (int rg = 0; rg < 4; ++rg)
          sm.l[(q * 4 + rg) * 132 + col] = acc2[jj][rg] + bo;
      }
      __syncthreads();
      {
        int row = tid >> 4, seg = tid & 15;
        const float* lr = &sm.l[row * 132 + seg * 8];
        float x[8];
        float m = -3.0e38f;
#pragma unroll
        for (int i = 0; i < 8; ++i) { x[i] = lr[i]; m = fmaxf(m, x[i]); }
#pragma unroll
        for (int d = 1; d < 16; d <<= 1) m = fmaxf(m, __shfl_xor(m, d, 16));
        float s = 0.0f;
#pragma unroll
        for (int i = 0; i < 8; ++i) s += __expf(x[i] - m);
#pragma unroll
        for (int d = 1; d < 16; d <<= 1) s += __shfl_xor(s, d, 16);
        float lg = m + __logf(s);
        float* dst = outp + (size_t)t * (BB * VV) + (size_t)(rb + row) * VV + seg * 8;
        f32x4 o0, o1;
#pragma unroll
        for (int i = 0; i < 4; ++i) { o0[i] = x[i] - lg; o1[i] = x[4 + i] - lg; }
        *(f32x4*)dst = o0;
        *(f32x4*)(dst + 4) = o1;
      }
      __syncthreads();   // drains reads/stores for all waves before arrive
      if (tid == 0) arrive(bar2);
    }
  }
}

// ---------------- launcher ----------------
extern "C" void kernel_launch(void* const* d_in, const int* in_sizes, int n_in,
                              void* d_out, int out_size, void* d_ws, size_t ws_size,
                              hipStream_t stream) {
  // 0 encoder_outputs (unused), 1 encoder_hidden, 2 target_tensor, 3 embedding,
  // 4 W_ih, 5 W_hh, 6 b_ih, 7 b_hh, 8 W_out, 9 b_out   (all float32; tgt int32)
  const float* ehid = (const float*)d_in[1];
  const int*   tgt  = (const int*)d_in[2];
  const float* emb  = (const float*)d_in[3];
  const float* Wih  = (const float*)d_in[4];
  const float* Whh  = (const float*)d_in[5];
  const float* bih  = (const float*)d_in[6];
  const float* bhh  = (const float*)d_in[7];
  const float* Wout = (const float*)d_in[8];
  const float* bout = (const float*)d_in[9];
  float* outp = (float*)d_out;

  // workspace carve: 6,689,280 B, offsets 256B-aligned
  char* ws = (char*)d_ws;
  float*  gi     = (float*)(ws + 0);            //   786,432 B
  __bf16* hb0    = (__bf16*)(ws + 786432);      // 2,097,152 B
  __bf16* hb1    = (__bf16*)(ws + 2883584);     // 2,097,152 B
  __bf16* Whh_b  = (__bf16*)(ws + 4980736);     // 1,572,864 B
  __bf16* Wout_b = (__bf16*)(ws + 6553600);     //   131,072 B
  float*  bhhn_f = (float*)(ws + 6684672);      //     2,048 B
  float*  bout_f = (float*)(ws + 6686720);      //       512 B
  int*    bar    = (int*)(ws + 6687232);        //     2,048 B (16 grp x 2 ctrs, 64B apart)

  conv_w<<<3072, 256, 0, stream>>>(Whh, Wout, bhh, bout, Whh_b, Wout_b, bhhn_f, bout_f, bar);
  prep_gi<<<768, 256, 0, stream>>>(emb, Wih, bih, bhh, gi);
  prep_h0<<<4096, 256, 0, stream>>>(ehid, hb0);
  gru_persist<<<640, 256, 0, stream>>>(Whh_b, Wout_b, bhhn_f, bout_f, gi, tgt,
                                       ehid, hb0, hb1, bar, outp);
}